// Round 12
// baseline (39.900 us; speedup 1.0000x reference)
//
#include <hip/hip_runtime.h>

// out(p) = (49 - g·G)/8,  g = x/max(||x||_C,1e-8),
// G = 7x7 zero-padded box-sum of g (separable 7-tap H then V).
// Rolling-strip persistent waves: each wave owns a 64x32 strip, swept in 4
// steps of 8 rows. Wave-private bf16 h ring (16 slots) in LDS; center-g
// crosses the 3-row pipeline lag via register shuffles. No block barrier.
// Grid = 1024 blocks = 4 blocks/CU, all co-resident (no dispatch rounds).

typedef unsigned int u32;
typedef float f32x2 __attribute__((ext_vector_type(2)));
typedef float f32x4 __attribute__((ext_vector_type(4)));

#define EPS2 1e-16f   // 1/max(sqrt(n2),1e-8) == rsq(max(n2,1e-16))

__device__ __forceinline__ u32 packbf2(float a, float b) {
    // round-half-up bf16 pack (a=lo, b=hi) via v_perm_b32
    const u32 ua = __float_as_uint(a) + 0x8000u;
    const u32 ub = __float_as_uint(b) + 0x8000u;
    return __builtin_amdgcn_perm(ub, ua, 0x07060302u);
}
__device__ __forceinline__ float uplo(u32 u) { return __uint_as_float(u << 16); }
__device__ __forceinline__ float uphi(u32 u) { return __uint_as_float(u & 0xffff0000u); }
__device__ __forceinline__ f32x2 up2(u32 u) {
    f32x2 r; r.x = uplo(u); r.y = uphi(u); return r;
}
__device__ __forceinline__ f32x4 vmul(f32x4 v, float s) {
    f32x4 r; r[0]=v[0]*s; r[1]=v[1]*s; r[2]=v[2]*s; r[3]=v[3]*s; return r;
}

__global__ __launch_bounds__(256, 4) void mcnd_kernel(const float* __restrict__ x,
                                                      float* __restrict__ out,
                                                      int B, int H, int W) {
    // wave-private h ring: [wave][ch][slot][grp], uint4 = 8 bf16 cols. 24,576 B.
    __shared__ uint4 hring[4][3][16][8];

    const int HW = H * W;

    // grid: B img x 8 xstrips x 4 ystrips(128 rows) = 1024 blocks.
    // bijective XCD swizzle (1024 % 8 == 0).
    const int cpx  = gridDim.x >> 3;
    const int wgid = (blockIdx.x & 7) * cpx + (blockIdx.x >> 3);
    const int b    = wgid >> 5;                    // / 32 tiles per image
    const int t    = wgid & 31;
    const int tb   = t >> 3;                       // 128-row block strip
    const int tx   = t & 7;
    const int x0   = tx << 6;

    const int wv   = threadIdx.x >> 6;             // wave id: 32-row strip
    const int lane = threadIdx.x & 63;
    const int r    = lane >> 3;                    // row slot within step
    const int grp  = lane & 7;                     // 8-col group
    const int yw   = (tb << 7) + (wv << 5);        // wave's first out row

    const float* __restrict__ xb = x + (size_t)b * 3 * HW;

    // column geometry (cols gxl..gxl+15 cover out cols 8grp with +/-3 halo)
    const int   gxl   = x0 + (grp << 3) - 4;       // 16B-aligned
    const float lmask = (gxl >= 0) ? 1.f : 0.f;
    const float rmask = (gxl + 16 <= W) ? 1.f : 0.f;
    const int   gofL  = (gxl >= 0) ? gxl : 0;              // clamped, in-bounds
    const int   gofR  = (gxl + 16 <= W) ? (gxl + 12) : (W - 4);

    // process h-row n (global row yw+n): load, normalize, 7-tap H, write ring.
    // Optionally capture this row's center-g (packed bf16) into gcp[12].
    auto process = [&](int n, u32* gcp) {
        const int   gy  = yw + n;
        const float rmk = (gy >= 0 && gy < H) ? 1.f : 0.f;
        const int   gyc = gy < 0 ? 0 : (gy >= H ? H - 1 : gy);
        const float* rp0 = xb + (size_t)gyc * W;
        const float* rp1 = rp0 + HW;
        const float* rp2 = rp1 + HW;
        f32x4 a0 = *(const f32x4*)(rp0 + gofL);
        f32x4 a1 = *(const f32x4*)(rp0 + gxl + 4);
        f32x4 a2 = *(const f32x4*)(rp0 + gxl + 8);
        f32x4 a3 = *(const f32x4*)(rp0 + gofR);
        f32x4 b0 = *(const f32x4*)(rp1 + gofL);
        f32x4 b1 = *(const f32x4*)(rp1 + gxl + 4);
        f32x4 b2 = *(const f32x4*)(rp1 + gxl + 8);
        f32x4 b3 = *(const f32x4*)(rp1 + gofR);
        f32x4 c0 = *(const f32x4*)(rp2 + gofL);
        f32x4 c1 = *(const f32x4*)(rp2 + gxl + 4);
        f32x4 c2 = *(const f32x4*)(rp2 + gxl + 8);
        f32x4 c3 = *(const f32x4*)(rp2 + gofR);
        a0 = vmul(a0, lmask); b0 = vmul(b0, lmask); c0 = vmul(c0, lmask);
        a3 = vmul(a3, rmask); b3 = vmul(b3, rmask); c3 = vmul(c3, rmask);
        f32x4 i0, i1, i2, i3;
        {
            const f32x4 n0 = a0*a0 + b0*b0 + c0*c0;
            const f32x4 n1 = a1*a1 + b1*b1 + c1*c1;
            const f32x4 n2 = a2*a2 + b2*b2 + c2*c2;
            const f32x4 n3 = a3*a3 + b3*b3 + c3*c3;
#pragma unroll
            for (int e = 0; e < 4; ++e) {
                i0[e] = __builtin_amdgcn_rsqf(fmaxf(n0[e], EPS2)) * rmk;
                i1[e] = __builtin_amdgcn_rsqf(fmaxf(n1[e], EPS2)) * rmk;
                i2[e] = __builtin_amdgcn_rsqf(fmaxf(n2[e], EPS2)) * rmk;
                i3[e] = __builtin_amdgcn_rsqf(fmaxf(n3[e], EPS2)) * rmk;
            }
        }
        const int slot = n & 15;
        auto chan = [&](const f32x4& A0, const f32x4& A1, const f32x4& A2,
                        const f32x4& A3, int ch) {
            float cc[16];
#pragma unroll
            for (int e = 0; e < 4; ++e) {
                cc[e]      = A0[e] * i0[e];
                cc[4 + e]  = A1[e] * i1[e];
                cc[8 + e]  = A2[e] * i2[e];
                cc[12 + e] = A3[e] * i3[e];
            }
            float hp[8];
            hp[0] = cc[1]+cc[2]+cc[3]+cc[4]+cc[5]+cc[6]+cc[7];
#pragma unroll
            for (int m = 1; m < 8; ++m) hp[m] = hp[m-1] - cc[m] + cc[m+7];
            uint4 hwv;
            hwv.x = packbf2(hp[0], hp[1]); hwv.y = packbf2(hp[2], hp[3]);
            hwv.z = packbf2(hp[4], hp[5]); hwv.w = packbf2(hp[6], hp[7]);
            hring[wv][ch][slot][grp] = hwv;
            if (gcp) {                             // center g = local cols 4..11
                gcp[ch*4 + 0] = packbf2(cc[4],  cc[5]);
                gcp[ch*4 + 1] = packbf2(cc[6],  cc[7]);
                gcp[ch*4 + 2] = packbf2(cc[8],  cc[9]);
                gcp[ch*4 + 3] = packbf2(cc[10], cc[11]);
            }
        };
        chan(a0, a1, a2, a3, 0);
        chan(b0, b1, b2, b3, 1);
        chan(c0, c1, c2, c3, 2);
    };

    // vertical 7-tap + dot + store for step s with center-g ctr[12]
    auto vertical = [&](int s, const u32* ctr) {
        const int n0 = 8*s + r - 3;
        f32x2 D[4];
#pragma unroll
        for (int e = 0; e < 4; ++e) D[e] = f32x2{0.f, 0.f};
#pragma unroll
        for (int ch = 0; ch < 3; ++ch) {
            f32x2 sum[4];
#pragma unroll
            for (int e = 0; e < 4; ++e) sum[e] = f32x2{0.f, 0.f};
#pragma unroll
            for (int d = 0; d < 7; ++d) {
                const uint4 u = hring[wv][ch][(n0 + d) & 15][grp];
                sum[0] += up2(u.x); sum[1] += up2(u.y);
                sum[2] += up2(u.z); sum[3] += up2(u.w);
            }
#pragma unroll
            for (int e = 0; e < 4; ++e) D[e] += up2(ctr[ch*4 + e]) * sum[e];
        }
        f32x4 o0, o1;
#pragma unroll
        for (int e = 0; e < 4; ++e) {
            const f32x2 v = (f32x2{49.f, 49.f} - D[e]) * 0.125f;
            if (e < 2) { o0[2*e] = v.x; o0[2*e+1] = v.y; }
            else       { o1[2*(e-2)] = v.x; o1[2*(e-2)+1] = v.y; }
        }
        float* op = out + (size_t)b * HW + (size_t)(yw + 8*s + r) * W
                        + (x0 + (grp << 3));
        *(f32x4*)(op)     = o0;
        *(f32x4*)(op + 4) = o1;
    };

    u32 cur[12], prv[12];

    // ---- step 0: fill h(-3..10), output rows yw..yw+7 ----
    {
        u32 gB[12];
#pragma unroll
        for (int i = 0; i < 12; ++i) gB[i] = 0;
        process(3 + r, cur);                       // h(3..10); lane r -> g(3+r)
        if (lane < 48) process((lane >> 3) - 3, gB); // h(-3..2); lanes 24..47 -> g(0..2)
        asm volatile("s_waitcnt lgkmcnt(0)" ::: "memory");
        __builtin_amdgcn_sched_barrier(0);
        // center-g for out row r: r<3 <- gB of lane+24; r>=3 <- cur of lane-24
        u32 ctr[12];
        const int iA = (lane >= 24) ? lane - 24 : 0;
        const int iB = (lane < 24) ? lane + 24 : 47;
#pragma unroll
        for (int i = 0; i < 12; ++i) {
            const u32 tA = (u32)__shfl((int)cur[i], iA);
            const u32 tB = (u32)__shfl((int)gB[i],  iB);
            ctr[i] = (r < 3) ? tB : tA;
        }
        vertical(0, ctr);
#pragma unroll
        for (int i = 0; i < 12; ++i) prv[i] = cur[i];
    }

    // ---- steps 1..3: 8 new h rows each, output rows yw+8s..yw+8s+7 ----
#pragma unroll
    for (int s = 1; s < 4; ++s) {
        process(8*s + 3 + r, cur);                 // h(8s+3..8s+10)
        asm volatile("s_waitcnt lgkmcnt(0)" ::: "memory");
        __builtin_amdgcn_sched_barrier(0);
        // center-g(8s+r): r<3 <- prv of lane+40 ; r>=3 <- cur of lane-24.
        // source sets disjoint (lanes>=40 give prv, lanes<40 give cur).
        u32 ctr[12];
        const int idx = (r < 3) ? lane + 40 : lane - 24;
#pragma unroll
        for (int i = 0; i < 12; ++i) {
            const u32 mix = (lane >= 40) ? prv[i] : cur[i];
            ctr[i] = (u32)__shfl((int)mix, idx);
        }
        vertical(s, ctr);
#pragma unroll
        for (int i = 0; i < 12; ++i) prv[i] = cur[i];
    }
}

extern "C" void kernel_launch(void* const* d_in, const int* in_sizes, int n_in,
                              void* d_out, int out_size, void* d_ws, size_t ws_size,
                              hipStream_t stream) {
    (void)n_in; (void)d_ws; (void)ws_size; (void)out_size;
    const float* x = (const float*)d_in[0];
    float* out = (float*)d_out;

    const int H = 512, W = 512, C = 3;
    const int B = in_sizes[0] / (C * H * W);       // 32

    const int blocks = B * (W >> 6) * (H >> 7);    // 32*8*4 = 1024
    mcnd_kernel<<<blocks, 256, 0, stream>>>(x, out, B, H, W);
}

// Round 13
// 35.452 us; speedup vs baseline: 1.1255x; 1.1255x over previous
//
#include <hip/hip_runtime.h>

// out(p) = (49 - g·G)/8,  g = x/max(||x||_C,1e-8),
// G = 7x7 zero-padded box-sum of g (separable 7-tap H then V).
// Wave-autonomous 64x8 tiles, NO block barrier. Both row-batches' global
// loads are issued back-to-back BEFORE either compute: compute A runs with
// batch B's 12 loads still in flight (single exposed memory wait per wave).
// LDS layout [hr][grp]: grp innermost -> wave b128 ops are conflict-free.

typedef unsigned int u32;
typedef float f32x2 __attribute__((ext_vector_type(2)));
typedef float f32x4 __attribute__((ext_vector_type(4)));

#define EPS2 1e-16f   // 1/max(sqrt(n2),1e-8) == rsq(max(n2,1e-16))

constexpr int HR = 14;   // h rows per wave tile (8 out rows + 6 halo)

__device__ __forceinline__ u32 packbf2(float a, float b) {
    // round-half-up bf16 pack (a=lo, b=hi) via v_perm_b32
    const u32 ua = __float_as_uint(a) + 0x8000u;
    const u32 ub = __float_as_uint(b) + 0x8000u;
    return __builtin_amdgcn_perm(ub, ua, 0x07060302u);
}
__device__ __forceinline__ float uplo(u32 u) { return __uint_as_float(u << 16); }
__device__ __forceinline__ float uphi(u32 u) { return __uint_as_float(u & 0xffff0000u); }
__device__ __forceinline__ f32x2 up2(u32 u) {
    f32x2 r; r.x = uplo(u); r.y = uphi(u); return r;
}
__device__ __forceinline__ f32x4 vmul(f32x4 v, float s) {
    f32x4 r; r[0]=v[0]*s; r[1]=v[1]*s; r[2]=v[2]*s; r[3]=v[3]*s; return r;
}

struct Rows {
    f32x4 a0, a1, a2, a3;    // ch0: 16 cols
    f32x4 b0, b1, b2, b3;    // ch1
    f32x4 c0, c1, c2, c3;    // ch2
    float rmk;               // row in-image mask
};

__global__ __launch_bounds__(256, 3) void mcnd_kernel(const float* __restrict__ x,
                                                      float* __restrict__ out,
                                                      int B, int H, int W) {
    // wave-private h: [wave][ch][hr][grp], uint4 = 8 bf16 cols. 21,504 B.
    __shared__ uint4 hsh[4][3][HR][8];

    const int HW = H * W;
    const int tilesX = W >> 6;                     // 8
    const int tilesPerImg = tilesX * (H >> 5);     // 128

    // bijective XCD swizzle (grid 4096 % 8 == 0)
    const int cpx  = gridDim.x >> 3;
    const int wgid = (blockIdx.x & 7) * cpx + (blockIdx.x >> 3);
    const int b    = wgid / tilesPerImg;
    const int t    = wgid % tilesPerImg;
    const int ty   = t / tilesX;
    const int tx   = t - ty * tilesX;
    const int x0   = tx << 6;

    const int wv   = threadIdx.x >> 6;             // wave id: 8-row strip
    const int lane = threadIdx.x & 63;
    const int r    = lane >> 3;                    // out row within strip
    const int grp  = lane & 7;                     // 8-col group
    const int yw   = (ty << 5) + (wv << 3);        // wave's first out row

    const float* __restrict__ xb = x + (size_t)b * 3 * HW;

    // column geometry (cols gxl..gxl+15 cover out cols 8grp with +/-3 halo)
    const int   gxl   = x0 + (grp << 3) - 4;       // 16B-aligned
    const float lmask = (gxl >= 0) ? 1.f : 0.f;
    const float rmask = (gxl + 16 <= W) ? 1.f : 0.f;
    const int   gofL  = (gxl >= 0) ? gxl : 0;              // clamped, in-bounds
    const int   gofR  = (gxl + 16 <= W) ? (gxl + 12) : (W - 4);

    auto loadrows = [&](int hr, Rows& R) {
        const int gy  = yw + hr - 3;
        R.rmk = (gy >= 0 && gy < H) ? 1.f : 0.f;
        const int gyc = gy < 0 ? 0 : (gy >= H ? H - 1 : gy);
        const float* rp0 = xb + (size_t)gyc * W;
        const float* rp1 = rp0 + HW;
        const float* rp2 = rp1 + HW;
        R.a0 = *(const f32x4*)(rp0 + gofL);
        R.a1 = *(const f32x4*)(rp0 + gxl + 4);
        R.a2 = *(const f32x4*)(rp0 + gxl + 8);
        R.a3 = *(const f32x4*)(rp0 + gofR);
        R.b0 = *(const f32x4*)(rp1 + gofL);
        R.b1 = *(const f32x4*)(rp1 + gxl + 4);
        R.b2 = *(const f32x4*)(rp1 + gxl + 8);
        R.b3 = *(const f32x4*)(rp1 + gofR);
        R.c0 = *(const f32x4*)(rp2 + gofL);
        R.c1 = *(const f32x4*)(rp2 + gxl + 4);
        R.c2 = *(const f32x4*)(rp2 + gxl + 8);
        R.c3 = *(const f32x4*)(rp2 + gofR);
    };

    u32 gc0[4], gc1[4], gc2[4];                    // center g, packed bf16

    auto computeRows = [&](Rows& R, int hr, bool capture) {
        // zero out-of-image column chunks (finite values -> 0*v == 0)
        f32x4 A0 = vmul(R.a0, lmask), B0 = vmul(R.b0, lmask), C0 = vmul(R.c0, lmask);
        f32x4 A3 = vmul(R.a3, rmask), B3 = vmul(R.b3, rmask), C3 = vmul(R.c3, rmask);
        f32x4 i0, i1, i2, i3;
        {
            const f32x4 n0 = A0*A0 + B0*B0 + C0*C0;
            const f32x4 n1 = R.a1*R.a1 + R.b1*R.b1 + R.c1*R.c1;
            const f32x4 n2 = R.a2*R.a2 + R.b2*R.b2 + R.c2*R.c2;
            const f32x4 n3 = A3*A3 + B3*B3 + C3*C3;
#pragma unroll
            for (int e = 0; e < 4; ++e) {
                i0[e] = __builtin_amdgcn_rsqf(fmaxf(n0[e], EPS2)) * R.rmk;
                i1[e] = __builtin_amdgcn_rsqf(fmaxf(n1[e], EPS2)) * R.rmk;
                i2[e] = __builtin_amdgcn_rsqf(fmaxf(n2[e], EPS2)) * R.rmk;
                i3[e] = __builtin_amdgcn_rsqf(fmaxf(n3[e], EPS2)) * R.rmk;
            }
        }
        auto chan = [&](const f32x4& V0, const f32x4& V1, const f32x4& V2,
                        const f32x4& V3, int ch, u32* gcp) {
            float cc[16];
#pragma unroll
            for (int e = 0; e < 4; ++e) {
                cc[e]      = V0[e] * i0[e];
                cc[4 + e]  = V1[e] * i1[e];
                cc[8 + e]  = V2[e] * i2[e];
                cc[12 + e] = V3[e] * i3[e];
            }
            // h for out col 8grp+m: staged cols m+1..m+7
            float hp[8];
            hp[0] = cc[1]+cc[2]+cc[3]+cc[4]+cc[5]+cc[6]+cc[7];
#pragma unroll
            for (int m = 1; m < 8; ++m) hp[m] = hp[m-1] - cc[m] + cc[m+7];
            uint4 hwv;
            hwv.x = packbf2(hp[0], hp[1]); hwv.y = packbf2(hp[2], hp[3]);
            hwv.z = packbf2(hp[4], hp[5]); hwv.w = packbf2(hp[6], hp[7]);
            hsh[wv][ch][hr][grp] = hwv;
            if (gcp) {                             // center g = local cols 4..11
                gcp[0] = packbf2(cc[4],  cc[5]);
                gcp[1] = packbf2(cc[6],  cc[7]);
                gcp[2] = packbf2(cc[8],  cc[9]);
                gcp[3] = packbf2(cc[10], cc[11]);
            }
        };
        chan(A0,   R.a1, R.a2, A3,   0, capture ? gc0 : nullptr);
        chan(B0,   R.b1, R.b2, B3,   1, capture ? gc1 : nullptr);
        chan(C0,   R.c1, R.c2, C3,   2, capture ? gc2 : nullptr);
    };

    // ---- issue ALL global loads first (B's stay in flight under compute A) ----
    const int rrB = lane >> 3;                     // 0..7
    const int hrB = (lane < 48) ? (rrB < 3 ? rrB : rrB + 8) : 0;  // halo rows
    Rows RA, RB;
    loadrows(r + 3, RA);                           // batch A: own output row
    loadrows(hrB,  RB);                            // batch B: halo (lanes>=48 dup)

    computeRows(RA, r + 3, true);                  // waits A only (vmcnt(12))
    if (lane < 48) computeRows(RB, hrB, false);    // halo rows {0,1,2,11,12,13}

    // wave-local fence instead of __syncthreads: this wave only reads hsh[wv],
    // written by its own (lockstep) lanes. Order ds_writes before ds_reads.
    asm volatile("s_waitcnt lgkmcnt(0)" ::: "memory");
    __builtin_amdgcn_sched_barrier(0);

    // ---- vertical 7-tap + dot + store (f32x2 ops -> v_pk_add/fma_f32) ----
    f32x2 D[4];
#pragma unroll
    for (int e = 0; e < 4; ++e) D[e] = f32x2{0.f, 0.f};
    auto vch = [&](int ch, const u32* gcp) {
        f32x2 s[4];
#pragma unroll
        for (int e = 0; e < 4; ++e) s[e] = f32x2{0.f, 0.f};
#pragma unroll
        for (int d = 0; d < 7; ++d) {
            const uint4 u = hsh[wv][ch][r + d][grp];
            s[0] += up2(u.x);
            s[1] += up2(u.y);
            s[2] += up2(u.z);
            s[3] += up2(u.w);
        }
#pragma unroll
        for (int e = 0; e < 4; ++e) D[e] += up2(gcp[e]) * s[e];
    };
    vch(0, gc0); vch(1, gc1); vch(2, gc2);

    f32x4 o0, o1;
#pragma unroll
    for (int e = 0; e < 4; ++e) {
        const f32x2 v = (f32x2{49.f, 49.f} - D[e]) * 0.125f;
        if (e < 2) { o0[2*e] = v.x; o0[2*e + 1] = v.y; }
        else       { o1[2*(e-2)] = v.x; o1[2*(e-2) + 1] = v.y; }
    }
    float* op = out + (size_t)b * HW + (size_t)(yw + r) * W + (x0 + (grp << 3));
    *(f32x4*)(op)     = o0;                        // 8 lanes = 256B span
    *(f32x4*)(op + 4) = o1;
}

extern "C" void kernel_launch(void* const* d_in, const int* in_sizes, int n_in,
                              void* d_out, int out_size, void* d_ws, size_t ws_size,
                              hipStream_t stream) {
    (void)n_in; (void)d_ws; (void)ws_size; (void)out_size;
    const float* x = (const float*)d_in[0];
    float* out = (float*)d_out;

    const int H = 512, W = 512, C = 3;
    const int B = in_sizes[0] / (C * H * W);       // 32

    const int tilesPerImg = (W >> 6) * (H >> 5);   // 128
    mcnd_kernel<<<B * tilesPerImg, 256, 0, stream>>>(x, out, B, H, W);
}

// Round 14
// 31.522 us; speedup vs baseline: 1.2658x; 1.1247x over previous
//
#include <hip/hip_runtime.h>

// out(p) = (49 - g·G)/8,  g = x/max(||x||_C,1e-8),
// G = 7x7 zero-padded box-sum of g (separable 7-tap H then V).
// Wave-autonomous 64x16 tiles (2 out rows/lane), NO block barrier.
// 22 h-rows per 16 out rows (1.375x halo) vs 14/8 (1.75x) previously.
// LDS [hr][grp] (grp innermost) -> wave b128 ops conflict-free.
// launch_bounds(256,3): VGPR cap 170 so the 2-row state cannot spill
// (round-10's 64x16 attempt spilled at the default cap).

typedef unsigned int u32;
typedef float f32x2 __attribute__((ext_vector_type(2)));
typedef float f32x4 __attribute__((ext_vector_type(4)));

#define EPS2 1e-16f   // 1/max(sqrt(n2),1e-8) == rsq(max(n2,1e-16))

constexpr int HRN = 22;   // h rows per wave tile (16 out rows + 6 halo)

__device__ __forceinline__ u32 packbf2(float a, float b) {
    // round-half-up bf16 pack (a=lo, b=hi) via v_perm_b32
    const u32 ua = __float_as_uint(a) + 0x8000u;
    const u32 ub = __float_as_uint(b) + 0x8000u;
    return __builtin_amdgcn_perm(ub, ua, 0x07060302u);
}
__device__ __forceinline__ float uplo(u32 u) { return __uint_as_float(u << 16); }
__device__ __forceinline__ float uphi(u32 u) { return __uint_as_float(u & 0xffff0000u); }
__device__ __forceinline__ f32x2 up2(u32 u) {
    f32x2 r; r.x = uplo(u); r.y = uphi(u); return r;
}
__device__ __forceinline__ f32x4 vmul(f32x4 v, float s) {
    f32x4 r; r[0]=v[0]*s; r[1]=v[1]*s; r[2]=v[2]*s; r[3]=v[3]*s; return r;
}

__global__ __launch_bounds__(256, 3) void mcnd_kernel(const float* __restrict__ x,
                                                      float* __restrict__ out,
                                                      int B, int H, int W) {
    // wave-private h: [wave][ch][hr][grp], uint4 = 8 bf16 cols. 33,792 B.
    __shared__ uint4 hsh[4][3][HRN][8];

    const int HW = H * W;
    const int tilesX = W >> 6;                     // 8  (block tile 64x64)
    const int tilesPerImg = tilesX * (H >> 6);     // 64

    // bijective XCD swizzle (grid 2048 % 8 == 0)
    const int cpx  = gridDim.x >> 3;
    const int wgid = (blockIdx.x & 7) * cpx + (blockIdx.x >> 3);
    const int b    = wgid / tilesPerImg;
    const int t    = wgid % tilesPerImg;
    const int ty   = t / tilesX;
    const int tx   = t - ty * tilesX;
    const int x0   = tx << 6;

    const int wv   = threadIdx.x >> 6;             // wave id: 16-row strip
    const int lane = threadIdx.x & 63;
    const int r2   = lane >> 3;                    // 0..7 -> out rows 2r2, 2r2+1
    const int grp  = lane & 7;                     // 8-col group
    const int yw   = (ty << 6) + (wv << 4);        // wave's first out row

    const float* __restrict__ xb = x + (size_t)b * 3 * HW;

    // column geometry (cols gxl..gxl+15 cover out cols 8grp with +/-3 halo)
    const int   gxl   = x0 + (grp << 3) - 4;       // 16B-aligned
    const float lmask = (gxl >= 0) ? 1.f : 0.f;
    const float rmask = (gxl + 16 <= W) ? 1.f : 0.f;
    const int   gofL  = (gxl >= 0) ? gxl : 0;              // clamped, in-bounds
    const int   gofR  = (gxl + 16 <= W) ? (gxl + 12) : (W - 4);

    u32 gA0[4], gA1[4], gA2[4];                    // center g, out row 2r2
    u32 gB0[4], gB1[4], gB2[4];                    // center g, out row 2r2+1

    // h-row hr corresponds to global row yw + hr - 3
    auto process = [&](int hr, u32* cp0, u32* cp1, u32* cp2) {
        const int   gy  = yw + hr - 3;
        const float rmk = (gy >= 0 && gy < H) ? 1.f : 0.f;
        const int   gyc = gy < 0 ? 0 : (gy >= H ? H - 1 : gy);
        const float* rp0 = xb + (size_t)gyc * W;
        const float* rp1 = rp0 + HW;
        const float* rp2 = rp1 + HW;
        // unconditional loads from clamped (always valid) addresses
        f32x4 a0 = *(const f32x4*)(rp0 + gofL);
        f32x4 a1 = *(const f32x4*)(rp0 + gxl + 4);
        f32x4 a2 = *(const f32x4*)(rp0 + gxl + 8);
        f32x4 a3 = *(const f32x4*)(rp0 + gofR);
        f32x4 b0 = *(const f32x4*)(rp1 + gofL);
        f32x4 b1 = *(const f32x4*)(rp1 + gxl + 4);
        f32x4 b2 = *(const f32x4*)(rp1 + gxl + 8);
        f32x4 b3 = *(const f32x4*)(rp1 + gofR);
        f32x4 c0 = *(const f32x4*)(rp2 + gofL);
        f32x4 c1 = *(const f32x4*)(rp2 + gxl + 4);
        f32x4 c2 = *(const f32x4*)(rp2 + gxl + 8);
        f32x4 c3 = *(const f32x4*)(rp2 + gofR);
        // zero out-of-image column chunks (finite values -> 0*v == 0)
        a0 = vmul(a0, lmask); b0 = vmul(b0, lmask); c0 = vmul(c0, lmask);
        a3 = vmul(a3, rmask); b3 = vmul(b3, rmask); c3 = vmul(c3, rmask);
        // per-column inverse norm (row mask folded in)
        f32x4 i0, i1, i2, i3;
        {
            const f32x4 n0 = a0*a0 + b0*b0 + c0*c0;
            const f32x4 n1 = a1*a1 + b1*b1 + c1*c1;
            const f32x4 n2 = a2*a2 + b2*b2 + c2*c2;
            const f32x4 n3 = a3*a3 + b3*b3 + c3*c3;
#pragma unroll
            for (int e = 0; e < 4; ++e) {
                i0[e] = __builtin_amdgcn_rsqf(fmaxf(n0[e], EPS2)) * rmk;
                i1[e] = __builtin_amdgcn_rsqf(fmaxf(n1[e], EPS2)) * rmk;
                i2[e] = __builtin_amdgcn_rsqf(fmaxf(n2[e], EPS2)) * rmk;
                i3[e] = __builtin_amdgcn_rsqf(fmaxf(n3[e], EPS2)) * rmk;
            }
        }
        auto chan = [&](const f32x4& A0, const f32x4& A1, const f32x4& A2,
                        const f32x4& A3, int ch, u32* gcp) {
            float cc[16];
#pragma unroll
            for (int e = 0; e < 4; ++e) {
                cc[e]      = A0[e] * i0[e];
                cc[4 + e]  = A1[e] * i1[e];
                cc[8 + e]  = A2[e] * i2[e];
                cc[12 + e] = A3[e] * i3[e];
            }
            // h for out col 8grp+m: staged cols m+1..m+7
            float hp[8];
            hp[0] = cc[1]+cc[2]+cc[3]+cc[4]+cc[5]+cc[6]+cc[7];
#pragma unroll
            for (int m = 1; m < 8; ++m) hp[m] = hp[m-1] - cc[m] + cc[m+7];
            uint4 hwv;
            hwv.x = packbf2(hp[0], hp[1]); hwv.y = packbf2(hp[2], hp[3]);
            hwv.z = packbf2(hp[4], hp[5]); hwv.w = packbf2(hp[6], hp[7]);
            hsh[wv][ch][hr][grp] = hwv;
            if (gcp) {                             // center g = local cols 4..11
                gcp[0] = packbf2(cc[4],  cc[5]);
                gcp[1] = packbf2(cc[6],  cc[7]);
                gcp[2] = packbf2(cc[8],  cc[9]);
                gcp[3] = packbf2(cc[10], cc[11]);
            }
        };
        chan(a0, a1, a2, a3, 0, cp0);
        chan(b0, b1, b2, b3, 1, cp1);
        chan(c0, c1, c2, c3, 2, cp2);
    };

    // own output rows: hr = 2r2+3 (out row 2r2), hr = 2r2+4 (out row 2r2+1)
    process(2*r2 + 3, gA0, gA1, gA2);
    process(2*r2 + 4, gB0, gB1, gB2);
    // halo rows {0,1,2,19,20,21} on lanes 0..47
    if (lane < 48) {
        const int rr = lane >> 3;                  // 0..5
        process(rr < 3 ? rr : rr + 16, nullptr, nullptr, nullptr);
    }
    // wave-local fence instead of __syncthreads (wave reads only hsh[wv])
    asm volatile("s_waitcnt lgkmcnt(0)" ::: "memory");
    __builtin_amdgcn_sched_barrier(0);

    // ---- vertical 7-tap, sliding over the 2 out rows; f32x2 math ----
    f32x2 D0[4], D1[4];
#pragma unroll
    for (int e = 0; e < 4; ++e) { D0[e] = f32x2{0.f,0.f}; D1[e] = f32x2{0.f,0.f}; }
    auto vch = [&](int ch, const u32* ga, const u32* gb) {
        const uint4 u0 = hsh[wv][ch][2*r2][grp];
        f32x2 s0 = up2(u0.x), s1 = up2(u0.y), s2 = up2(u0.z), s3 = up2(u0.w);
#pragma unroll
        for (int d = 1; d < 7; ++d) {
            const uint4 u = hsh[wv][ch][2*r2 + d][grp];
            s0 += up2(u.x); s1 += up2(u.y); s2 += up2(u.z); s3 += up2(u.w);
        }
        const uint4 u7 = hsh[wv][ch][2*r2 + 7][grp];
        // row 2r2: window hr 2r2..2r2+6 = s ; row 2r2+1: s - u0 + u7
        D0[0] += up2(ga[0]) * s0;
        D0[1] += up2(ga[1]) * s1;
        D0[2] += up2(ga[2]) * s2;
        D0[3] += up2(ga[3]) * s3;
        D1[0] += up2(gb[0]) * (s0 - up2(u0.x) + up2(u7.x));
        D1[1] += up2(gb[1]) * (s1 - up2(u0.y) + up2(u7.y));
        D1[2] += up2(gb[2]) * (s2 - up2(u0.z) + up2(u7.z));
        D1[3] += up2(gb[3]) * (s3 - up2(u0.w) + up2(u7.w));
    };
    vch(0, gA0, gB0); vch(1, gA1, gB1); vch(2, gA2, gB2);

    f32x4 o00, o01, o10, o11;
#pragma unroll
    for (int e = 0; e < 4; ++e) {
        const f32x2 v0 = (f32x2{49.f, 49.f} - D0[e]) * 0.125f;
        const f32x2 v1 = (f32x2{49.f, 49.f} - D1[e]) * 0.125f;
        if (e < 2) { o00[2*e] = v0.x; o00[2*e+1] = v0.y;
                     o10[2*e] = v1.x; o10[2*e+1] = v1.y; }
        else       { o01[2*(e-2)] = v0.x; o01[2*(e-2)+1] = v0.y;
                     o11[2*(e-2)] = v1.x; o11[2*(e-2)+1] = v1.y; }
    }
    float* op = out + (size_t)b * HW + (size_t)(yw + 2*r2) * W + (x0 + (grp << 3));
    *(f32x4*)(op)         = o00;                   // 8 lanes = 256B span
    *(f32x4*)(op + 4)     = o01;
    *(f32x4*)(op + W)     = o10;
    *(f32x4*)(op + W + 4) = o11;
}

extern "C" void kernel_launch(void* const* d_in, const int* in_sizes, int n_in,
                              void* d_out, int out_size, void* d_ws, size_t ws_size,
                              hipStream_t stream) {
    (void)n_in; (void)d_ws; (void)ws_size; (void)out_size;
    const float* x = (const float*)d_in[0];
    float* out = (float*)d_out;

    const int H = 512, W = 512, C = 3;
    const int B = in_sizes[0] / (C * H * W);       // 32

    const int tilesPerImg = (W >> 6) * (H >> 6);   // 64
    mcnd_kernel<<<B * tilesPerImg, 256, 0, stream>>>(x, out, B, H, W);
}